// Round 9
// baseline (1443.312 us; speedup 1.0000x reference)
//
#include <hip/hip_runtime.h>
#include <math.h>

// ---------- wave-wide sum (64 lanes), fixed deterministic order ----------
__device__ __forceinline__ float wred(float s) {
  #pragma unroll
  for (int o = 32; o > 0; o >>= 1) s += __shfl_xor(s, o, 64);
  return s;
}

__device__ __forceinline__ float fma4(float4 w, float4 a, float acc) {
  return fmaf(w.w, a.w, fmaf(w.z, a.z, fmaf(w.y, a.y, fmaf(w.x, a.x, acc))));
}

// ==================== TR=32 helpers (k_table only, cold path) ====================
__device__ __forceinline__ void ln_rows32(float (*A)[256], const float* __restrict__ gg,
                                          const float* __restrict__ bb, int t) {
  const int w = t >> 6, l = t & 63;
  const float g0 = gg[l], g1 = gg[l + 64], g2 = gg[l + 128], g3 = gg[l + 192];
  const float c0 = bb[l], c1 = bb[l + 64], c2 = bb[l + 128], c3 = bb[l + 192];
  #pragma unroll
  for (int rr = 0; rr < 8; ++rr) {
    const int r = w * 8 + rr;
    const float v0 = A[r][l], v1 = A[r][l + 64], v2 = A[r][l + 128], v3 = A[r][l + 192];
    float s = ((v0 + v1) + v2) + v3;
    s = wred(s);
    const float mu = s * (1.f / 256.f);
    const float d0 = v0 - mu, d1 = v1 - mu, d2 = v2 - mu, d3 = v3 - mu;
    float s2 = fmaf(d3, d3, fmaf(d2, d2, fmaf(d1, d1, d0 * d0)));
    s2 = wred(s2);
    const float var = s2 * (1.f / 256.f);
    const float rs = 1.f / sqrtf(var + 1e-5f);
    A[r][l]       = (d0 * rs) * g0 + c0;
    A[r][l + 64]  = (d1 * rs) * g1 + c1;
    A[r][l + 128] = (d2 * rs) * g2 + c2;
    A[r][l + 192] = (d3 * rs) * g3 + c3;
  }
  __syncthreads();
}

__device__ __forceinline__ void hidden_layer32(float (*A)[256], const float* __restrict__ W,
                                               const float* __restrict__ B, int t) {
  const int g = t >> 7;
  const int j0 = t & 127, j1 = j0 + 128;
  const float4* W0 = (const float4*)(W + j0 * 256);
  const float4* W1 = (const float4*)(W + j1 * 256);
  float acc0[16], acc1[16];
  #pragma unroll
  for (int r = 0; r < 16; ++r) { acc0[r] = 0.f; acc1[r] = 0.f; }
  #pragma unroll 2
  for (int kq = 0; kq < 64; ++kq) {
    const float4 wq0 = W0[kq], wq1 = W1[kq];
    #pragma unroll
    for (int rr = 0; rr < 16; ++rr) {
      const float4 a = *(const float4*)&A[g * 16 + rr][kq * 4];
      acc0[rr] = fma4(wq0, a, acc0[rr]);
      acc1[rr] = fma4(wq1, a, acc1[rr]);
    }
  }
  const float bb0 = B[j0], bb1 = B[j1];
  __syncthreads();
  #pragma unroll
  for (int rr = 0; rr < 16; ++rr) {
    const int r = g * 16 + rr;
    A[r][j0] = fmaxf(acc0[rr] + bb0, 0.f);
    A[r][j1] = fmaxf(acc1[rr] + bb1, 0.f);
  }
  __syncthreads();
}

// ==================== k_enc: 1 wave, 16 rows, row-group split, 8 cols/lane ====================
// Lane group gr = l>>5 owns rows gr*8..gr*8+7; lane owns cols c0..c0+7 (c0=(l&31)*8).
// A[16][256] activations only (16 KB). LN fully via intra-group shuffles.

// LayerNorm, centered two-pass (reference shape), on acc[64] = 8 rows x 8 cols.
// Row partials reduced across the 32-lane group by 5-step xor-shuffle (stays in half-wave).
__device__ __forceinline__ void ln64s(float* acc,
                                      const float* __restrict__ gg,
                                      const float* __restrict__ bb, int c0) {
  float p[8], mu[8];
  // ---- pass 1: mean ----
  #pragma unroll
  for (int rr = 0; rr < 8; ++rr) {
    const float* a = &acc[rr * 8];
    p[rr] = (((a[0] + a[1]) + (a[2] + a[3])) + ((a[4] + a[5]) + (a[6] + a[7])));
  }
  #pragma unroll
  for (int o = 1; o <= 16; o <<= 1) {
    #pragma unroll
    for (int rr = 0; rr < 8; ++rr) p[rr] += __shfl_xor(p[rr], o, 64);
  }
  #pragma unroll
  for (int rr = 0; rr < 8; ++rr) mu[rr] = p[rr] * (1.f / 256.f);
  // ---- pass 2: centered variance ----
  #pragma unroll
  for (int rr = 0; rr < 8; ++rr) {
    const float* a = &acc[rr * 8];
    const float m = mu[rr];
    const float d0 = a[0] - m, d1 = a[1] - m, d2 = a[2] - m, d3 = a[3] - m;
    const float d4 = a[4] - m, d5 = a[5] - m, d6 = a[6] - m, d7 = a[7] - m;
    float s = d0 * d0;
    s = fmaf(d1, d1, s); s = fmaf(d2, d2, s); s = fmaf(d3, d3, s);
    s = fmaf(d4, d4, s); s = fmaf(d5, d5, s); s = fmaf(d6, d6, s); s = fmaf(d7, d7, s);
    p[rr] = s;
  }
  #pragma unroll
  for (int o = 1; o <= 16; o <<= 1) {
    #pragma unroll
    for (int rr = 0; rr < 8; ++rr) p[rr] += __shfl_xor(p[rr], o, 64);
  }
  // ---- normalize in registers: ((x-mu)*rs)*g + b ----
  float gv[8], bv[8];
  *(float4*)&gv[0] = *(const float4*)&gg[c0];
  *(float4*)&gv[4] = *(const float4*)&gg[c0 + 4];
  *(float4*)&bv[0] = *(const float4*)&bb[c0];
  *(float4*)&bv[4] = *(const float4*)&bb[c0 + 4];
  #pragma unroll
  for (int rr = 0; rr < 8; ++rr) {
    const float rs = 1.f / sqrtf(p[rr] * (1.f / 256.f) + 1e-5f);
    const float m = mu[rr];
    #pragma unroll
    for (int c = 0; c < 8; ++c)
      acc[rr * 8 + c] = ((acc[rr * 8 + c] - m) * rs) * gv[c] + bv[c];
  }
}

__device__ __forceinline__ void storeA64g(float (*A)[256], const float* acc, int gr8, int c0) {
  #pragma unroll
  for (int rr = 0; rr < 8; ++rr) {
    *(float4*)&A[gr8 + rr][c0] =
        make_float4(acc[rr * 8], acc[rr * 8 + 1], acc[rr * 8 + 2], acc[rr * 8 + 3]);
    *(float4*)&A[gr8 + rr][c0 + 4] =
        make_float4(acc[rr * 8 + 4], acc[rr * 8 + 5], acc[rr * 8 + 6], acc[rr * 8 + 7]);
  }
}

__global__ __launch_bounds__(64, 2) void k_enc(
    const float* __restrict__ x, const float* __restrict__ w0,
    const float* __restrict__ b0, const float* __restrict__ wt1,
    const float* __restrict__ wt2, const float* __restrict__ bh,
    const float* __restrict__ lng, const float* __restrict__ lnb,
    const float* __restrict__ wtout, const float* __restrict__ bout,
    float* __restrict__ z) {
  __shared__ float A[16][256];
  const int l = threadIdx.x;
  const int gr8 = (l >> 5) * 8;        // row group base (0 or 8)
  const int c0 = (l & 31) * 8;         // 8 owned columns
  const size_t rbase = (size_t)blockIdx.x * 16;
  float acc[64];

  { // layer 0: 3 -> 256, 8 rows x 8 cols per lane
    float wv[24], bv[8];
    #pragma unroll
    for (int i = 0; i < 6; ++i) *(float4*)&wv[i * 4] = *(const float4*)&w0[c0 * 3 + i * 4];
    *(float4*)&bv[0] = *(const float4*)&b0[c0];
    *(float4*)&bv[4] = *(const float4*)&b0[c0 + 4];
    #pragma unroll
    for (int rr = 0; rr < 8; ++rr) {
      const size_t r3 = (rbase + gr8 + rr) * 3;
      const float x0 = x[r3], x1 = x[r3 + 1], x2 = x[r3 + 2];
      #pragma unroll
      for (int c = 0; c < 8; ++c) {
        const float s = fmaf(wv[c * 3 + 2], x2, fmaf(wv[c * 3 + 1], x1, wv[c * 3] * x0));
        acc[rr * 8 + c] = fmaxf(s + bv[c], 0.f);
      }
    }
  }
  ln64s(acc, lng, lnb, c0);
  storeA64g(A, acc, gr8, c0);
  __syncthreads();

  // ---- two hidden layers: 8 rows x 8 cols per lane, full k, W + A ping-pong ----
  #pragma unroll 1
  for (int layer = 0; layer < 2; ++layer) {
    const float* __restrict__ WT = layer == 0 ? wt1 : wt2;
    const float* __restrict__ Bp = layer == 0 ? bh : bh + 256;

    #define LDWQ(buf, kqv) { \
      _Pragma("unroll") \
      for (int kk_ = 0; kk_ < 4; ++kk_) { \
        buf[kk_ * 2]     = *(const float4*)&WT[(size_t)((kqv) * 4 + kk_) * 256 + c0]; \
        buf[kk_ * 2 + 1] = *(const float4*)&WT[(size_t)((kqv) * 4 + kk_) * 256 + c0 + 4]; \
      } }
    #define LDAQ(buf, kqv) { \
      _Pragma("unroll") \
      for (int i_ = 0; i_ < 8; ++i_) buf[i_] = *(const float4*)&A[gr8 + i_][(kqv) * 4]; }
    #define FMAQ(abuf, wbuf) { \
      _Pragma("unroll") \
      for (int kk_ = 0; kk_ < 4; ++kk_) { \
        const float4 wlo_ = wbuf[kk_ * 2], whi_ = wbuf[kk_ * 2 + 1]; \
        _Pragma("unroll") \
        for (int i_ = 0; i_ < 8; ++i_) { \
          const float av_ = kk_ == 0 ? abuf[i_].x : kk_ == 1 ? abuf[i_].y : kk_ == 2 ? abuf[i_].z : abuf[i_].w; \
          acc[i_ * 8 + 0] = fmaf(av_, wlo_.x, acc[i_ * 8 + 0]); \
          acc[i_ * 8 + 1] = fmaf(av_, wlo_.y, acc[i_ * 8 + 1]); \
          acc[i_ * 8 + 2] = fmaf(av_, wlo_.z, acc[i_ * 8 + 2]); \
          acc[i_ * 8 + 3] = fmaf(av_, wlo_.w, acc[i_ * 8 + 3]); \
          acc[i_ * 8 + 4] = fmaf(av_, whi_.x, acc[i_ * 8 + 4]); \
          acc[i_ * 8 + 5] = fmaf(av_, whi_.y, acc[i_ * 8 + 5]); \
          acc[i_ * 8 + 6] = fmaf(av_, whi_.z, acc[i_ * 8 + 6]); \
          acc[i_ * 8 + 7] = fmaf(av_, whi_.w, acc[i_ * 8 + 7]); \
        } } }

    #pragma unroll
    for (int i = 0; i < 64; ++i) acc[i] = 0.f;
    float4 wA[8], wB[8], aC[8], aN[8];
    LDWQ(wA, 0);
    LDAQ(aC, 0);
    #pragma unroll 1
    for (int kq = 0; kq < 64; kq += 2) {
      LDWQ(wB, kq + 1);
      LDAQ(aN, kq + 1);
      FMAQ(aC, wA);
      if (kq + 2 < 64) { LDWQ(wA, kq + 2); LDAQ(aC, kq + 2); }
      FMAQ(aN, wB);
    }
    #undef LDWQ
    #undef LDAQ
    #undef FMAQ
    { // bias + relu
      float bv[8];
      *(float4*)&bv[0] = *(const float4*)&Bp[c0];
      *(float4*)&bv[4] = *(const float4*)&Bp[c0 + 4];
      #pragma unroll
      for (int rr = 0; rr < 8; ++rr)
        #pragma unroll
        for (int c = 0; c < 8; ++c)
          acc[rr * 8 + c] = fmaxf(acc[rr * 8 + c] + bv[c], 0.f);
    }
    ln64s(acc, lng + 256 + layer * 256, lnb + 256 + layer * 256, c0);
    __syncthreads();              // all A-reads of this layer done before overwrite
    storeA64g(A, acc, gr8, c0);
    __syncthreads();
  }

  { // out layer 256 -> 64: 8 rows x 2 cols per lane, A+W ping-pong
    const int c0o = (l & 31) * 2;
    float o[16];
    #pragma unroll
    for (int i = 0; i < 16; ++i) o[i] = 0.f;
    #define LDAO(buf, kqv) { \
      _Pragma("unroll") \
      for (int i_ = 0; i_ < 8; ++i_) buf[i_] = *(const float4*)&A[gr8 + i_][(kqv) * 4]; }
    #define LDWO(buf, kqv) { \
      _Pragma("unroll") \
      for (int kk_ = 0; kk_ < 4; ++kk_) \
        buf[kk_] = *(const float2*)&wtout[(size_t)((kqv) * 4 + kk_) * 64 + c0o]; }
    #define FMAO(abuf, wbuf) { \
      _Pragma("unroll") \
      for (int kk_ = 0; kk_ < 4; ++kk_) { \
        const float2 wv_ = wbuf[kk_]; \
        _Pragma("unroll") \
        for (int i_ = 0; i_ < 8; ++i_) { \
          const float av_ = kk_ == 0 ? abuf[i_].x : kk_ == 1 ? abuf[i_].y : kk_ == 2 ? abuf[i_].z : abuf[i_].w; \
          o[i_ * 2]     = fmaf(av_, wv_.x, o[i_ * 2]); \
          o[i_ * 2 + 1] = fmaf(av_, wv_.y, o[i_ * 2 + 1]); \
        } } }
    float4 aC[8], aN[8];
    float2 wC[4], wN[4];
    LDAO(aC, 0); LDWO(wC, 0);
    #pragma unroll 1
    for (int kq = 0; kq < 64; kq += 2) {
      LDAO(aN, kq + 1); LDWO(wN, kq + 1);
      FMAO(aC, wC);
      if (kq + 2 < 64) { LDAO(aC, kq + 2); LDWO(wC, kq + 2); }
      FMAO(aN, wN);
    }
    #undef LDAO
    #undef LDWO
    #undef FMAO
    const float2 bb = *(const float2*)&bout[c0o];
    #pragma unroll
    for (int rr = 0; rr < 8; ++rr) {
      float2 st;
      st.x = o[rr * 2] + bb.x;
      st.y = o[rr * 2 + 1] + bb.y;
      *(float2*)&z[(rbase + gr8 + rr) * 64 + c0o] = st;
    }
  }
}

// ---------------- weight transpose: WT[k][j] = W[j][k] ----------------
__global__ __launch_bounds__(256) void k_wt(const float* __restrict__ wh,
                                            const float* __restrict__ wout,
                                            float* __restrict__ wt1, float* __restrict__ wt2,
                                            float* __restrict__ wtout) {
  const int b = blockIdx.x, t = threadIdx.x;
  if (b < 256) {
    wt1[b * 256 + t] = wh[t * 256 + b];
  } else if (b < 512) {
    const int k = b - 256;
    wt2[k * 256 + t] = wh[65536 + t * 256 + k];
  } else {
    const int k = (b - 512) * 4 + (t >> 6);
    const int j = t & 63;
    wtout[k * 64 + j] = wout[j * 256 + k];
  }
}

// -------- decode table: table[512][3] = dec(codebook), ne[512] = ||e||^2 --------
__global__ __launch_bounds__(256) void k_table(
    const float* __restrict__ cb, const float* __restrict__ w0,
    const float* __restrict__ b0, const float* __restrict__ wh,
    const float* __restrict__ bh, const float* __restrict__ lng,
    const float* __restrict__ lnb, const float* __restrict__ wout,
    const float* __restrict__ bout, float* __restrict__ table,
    float* __restrict__ ne) {
  __shared__ float A[32][256];
  __shared__ float cs[32][64];
  const int t = threadIdx.x;
  const int cbase = blockIdx.x * 32;
  {
    float4* d = (float4*)&cs[0][0];
    const float4* s = (const float4*)(cb + cbase * 64);
    d[t] = s[t];
    d[t + 256] = s[t + 256];
  }
  __syncthreads();
  if (t < 32) {
    float s = 0.f;
    #pragma unroll 8
    for (int k = 0; k < 64; ++k) s = fmaf(cs[t][k], cs[t][k], s);
    ne[cbase + t] = s;
  }
  {
    const float4* Wr = (const float4*)(w0 + t * 64);
    float acc[32];
    #pragma unroll
    for (int r = 0; r < 32; ++r) acc[r] = 0.f;
    for (int kq = 0; kq < 16; ++kq) {
      const float4 w = Wr[kq];
      #pragma unroll
      for (int r = 0; r < 32; ++r) {
        const float4 a = *(const float4*)&cs[r][kq * 4];
        acc[r] = fma4(w, a, acc[r]);
      }
    }
    const float bb = b0[t];
    #pragma unroll
    for (int r = 0; r < 32; ++r) A[r][t] = fmaxf(acc[r] + bb, 0.f);
  }
  __syncthreads();
  ln_rows32(A, lng, lnb, t);
  hidden_layer32(A, wh, bh, t);
  ln_rows32(A, lng + 256, lnb + 256, t);
  hidden_layer32(A, wh + 65536, bh + 256, t);
  ln_rows32(A, lng + 512, lnb + 512, t);
  if (t < 96) {
    const int r = t / 3, j = t - r * 3;
    const float4* Wr = (const float4*)(wout + j * 256);
    float s = 0.f;
    #pragma unroll 4
    for (int kq = 0; kq < 64; ++kq) {
      const float4 w = Wr[kq];
      const float4 a = *(const float4*)&A[r][kq * 4];
      s = fma4(w, a, s);
    }
    table[(cbase + r) * 3 + j] = s + bout[j];
  }
}

// ---- VQ: z (in zq_io) -> argmin, quantized in-place, recon gather, partials ----
__global__ __launch_bounds__(256) void k_vq(
    float* __restrict__ zq_io, const float* __restrict__ cb,
    const float* __restrict__ ne, const float* __restrict__ table,
    const float* __restrict__ x, float* __restrict__ recon,
    float* __restrict__ psr, float* __restrict__ psv) {
  __shared__ float red[256];
  const int t = threadIdx.x;
  const int row = blockIdx.x * 256 + t;
  float4 zf[16];
  {
    const float4* zp = (const float4*)(zq_io + (size_t)row * 64);
    #pragma unroll
    for (int q = 0; q < 16; ++q) zf[q] = zp[q];
  }
  float nz = 0.f;
  #pragma unroll
  for (int q = 0; q < 16; ++q) {
    nz = fmaf(zf[q].x, zf[q].x, nz);
    nz = fmaf(zf[q].y, zf[q].y, nz);
    nz = fmaf(zf[q].z, zf[q].z, nz);
    nz = fmaf(zf[q].w, zf[q].w, nz);
  }
  float dmin = INFINITY; int imin = 0;
  const float4* cbv = (const float4*)cb;
  for (int c = 0; c < 512; ++c) {
    float da = 0.f, db = 0.f;
    #pragma unroll
    for (int q = 0; q < 16; q += 2) {
      const float4 ea = cbv[c * 16 + q];
      const float4 eb = cbv[c * 16 + q + 1];
      da = fmaf(ea.x, zf[q].x, da);
      da = fmaf(ea.y, zf[q].y, da);
      da = fmaf(ea.z, zf[q].z, da);
      da = fmaf(ea.w, zf[q].w, da);
      db = fmaf(eb.x, zf[q + 1].x, db);
      db = fmaf(eb.y, zf[q + 1].y, db);
      db = fmaf(eb.z, zf[q + 1].z, db);
      db = fmaf(eb.w, zf[q + 1].w, db);
    }
    const float dot = da + db;
    const float d = (nz + ne[c]) - 2.f * dot;
    if (d < dmin) { dmin = d; imin = c; }
  }
  float sv = 0.f;
  {
    const float4* eq = (const float4*)(cb + imin * 64);
    float4* qo = (float4*)(zq_io + (size_t)row * 64);
    #pragma unroll
    for (int q = 0; q < 16; ++q) {
      const float4 e = eq[q];
      const float4 zz = zf[q];
      const float ax = e.x - zz.x, ay = e.y - zz.y, az = e.z - zz.z, aw = e.w - zz.w;
      sv = fmaf(ax, ax, sv); sv = fmaf(ay, ay, sv);
      sv = fmaf(az, az, sv); sv = fmaf(aw, aw, sv);
      float4 st;
      st.x = zz.x + ax; st.y = zz.y + ay; st.z = zz.z + az; st.w = zz.w + aw;
      qo[q] = st;
    }
  }
  const float r0 = table[imin * 3], r1 = table[imin * 3 + 1], r2 = table[imin * 3 + 2];
  recon[row * 3] = r0; recon[row * 3 + 1] = r1; recon[row * 3 + 2] = r2;
  const float e0 = r0 - x[row * 3], e1 = r1 - x[row * 3 + 1], e2 = r2 - x[row * 3 + 2];
  const float sr = fmaf(e2, e2, fmaf(e1, e1, e0 * e0));
  red[t] = sr; __syncthreads();
  #pragma unroll
  for (int o = 128; o > 0; o >>= 1) { if (t < o) red[t] += red[t + o]; __syncthreads(); }
  if (t == 0) psr[blockIdx.x] = red[0];
  __syncthreads();
  red[t] = sv; __syncthreads();
  #pragma unroll
  for (int o = 128; o > 0; o >>= 1) { if (t < o) red[t] += red[t + o]; __syncthreads(); }
  if (t == 0) psv[blockIdx.x] = red[0];
}

// ---------------- final scalar loss ----------------
__global__ __launch_bounds__(256) void k_loss(
    const float* __restrict__ psr, const float* __restrict__ psv,
    float* __restrict__ out) {
  __shared__ float ra[256], rb[256];
  const int t = threadIdx.x;
  const float sr = ((psr[t] + psr[t + 256]) + psr[t + 512]) + psr[t + 768];
  const float sv = ((psv[t] + psv[t + 256]) + psv[t + 512]) + psv[t + 768];
  ra[t] = sr; rb[t] = sv;
  __syncthreads();
  #pragma unroll
  for (int o = 128; o > 0; o >>= 1) {
    if (t < o) { ra[t] += ra[t + o]; rb[t] += rb[t + o]; }
    __syncthreads();
  }
  if (t == 0) {
    const float mr = ra[0] / 786432.f;
    const float mv = rb[0] * (1.f / 16777216.f);
    const float vq = 0.25f * mv + mv;
    out[0] = mr + vq;
  }
}

extern "C" void kernel_launch(void* const* d_in, const int* in_sizes, int n_in,
                              void* d_out, int out_size, void* d_ws, size_t ws_size,
                              hipStream_t stream) {
  const float* x        = (const float*)d_in[0];
  const float* enc_w0   = (const float*)d_in[1];
  const float* enc_b0   = (const float*)d_in[2];
  const float* enc_wh   = (const float*)d_in[3];
  const float* enc_bh   = (const float*)d_in[4];
  const float* enc_lng  = (const float*)d_in[5];
  const float* enc_lnb  = (const float*)d_in[6];
  const float* enc_wout = (const float*)d_in[7];
  const float* enc_bout = (const float*)d_in[8];
  const float* cb       = (const float*)d_in[9];
  const float* dec_w0   = (const float*)d_in[10];
  const float* dec_b0   = (const float*)d_in[11];
  const float* dec_wh   = (const float*)d_in[12];
  const float* dec_bh   = (const float*)d_in[13];
  const float* dec_lng  = (const float*)d_in[14];
  const float* dec_lnb  = (const float*)d_in[15];
  const float* dec_wout = (const float*)d_in[16];
  const float* dec_bout = (const float*)d_in[17];

  float* out   = (float*)d_out;
  float* recon = out;                       // [N,3]
  float* qbuf  = out + 786432;              // [N,64]: z, then quantized in place
  float* lossp = out + 786432 + 16777216;   // scalar

  // Transposed weights live in the recon region (written before k_enc reads them,
  // fully overwritten by k_vq afterwards -> deterministic across replays).
  float* wt1   = out;                       // 65536
  float* wt2   = out + 65536;               // 65536
  float* wtout = out + 131072;              // 16384   (total 147456 < 786432)

  float* ws    = (float*)d_ws;
  float* ne    = ws;          // 512
  float* table = ws + 512;    // 512*3
  float* psr   = ws + 2048;   // 1024
  float* psv   = ws + 3072;   // 1024

  k_wt<<<576, 256, 0, stream>>>(enc_wh, enc_wout, wt1, wt2, wtout);
  k_table<<<16, 256, 0, stream>>>(cb, dec_w0, dec_b0, dec_wh, dec_bh,
                                  dec_lng, dec_lnb, dec_wout, dec_bout,
                                  table, ne);
  k_enc<<<16384, 64, 0, stream>>>(x, enc_w0, enc_b0, wt1, wt2, enc_bh,
                                  enc_lng, enc_lnb, wtout, enc_bout, qbuf);
  k_vq<<<1024, 256, 0, stream>>>(qbuf, cb, ne, table, x, recon, psr, psv);
  k_loss<<<1, 256, 0, stream>>>(psr, psv, lossp);
}

// Round 10
// 1305.743 us; speedup vs baseline: 1.1054x; 1.1054x over previous
//
#include <hip/hip_runtime.h>
#include <math.h>

__device__ __forceinline__ float fma4(float4 w, float4 a, float acc) {
  return fmaf(w.w, a.w, fmaf(w.z, a.z, fmaf(w.y, a.y, fmaf(w.x, a.x, acc))));
}

// ==================== shared device helpers (1 wave, 16 rows, 8 cols/lane) ====================
// Lane group gr8 = (l>>5)*8 owns rows gr8..gr8+7; lane owns cols c0..c0+7 (c0=(l&31)*8).
// A[16][256] = 16 KB. LN scratch P aliased into A (rows 0..2): row stride 36, slots 0..31
// partials + slot 32 stat. Safe because every P write happens after the A tile has been
// fully consumed into registers (single in-order wave) and before storeA rewrites A.

// 256-FMA quad step: 8 rows x 8 cols, k-quad kq (A-read is 2-address broadcast).
__device__ __forceinline__ void quadf(const float (*A)[256], int kq, const float4* wbuf,
                                      float* acc, int gr8) {
  float4 a_[8];
  #pragma unroll
  for (int i = 0; i < 8; ++i) a_[i] = *(const float4*)&A[gr8 + i][kq * 4];
  #pragma unroll
  for (int kk = 0; kk < 4; ++kk) {
    const float4 wlo = wbuf[kk * 2], whi = wbuf[kk * 2 + 1];
    #pragma unroll
    for (int i = 0; i < 8; ++i) {
      const float av = kk == 0 ? a_[i].x : kk == 1 ? a_[i].y : kk == 2 ? a_[i].z : a_[i].w;
      acc[i * 8 + 0] = fmaf(av, wlo.x, acc[i * 8 + 0]);
      acc[i * 8 + 1] = fmaf(av, wlo.y, acc[i * 8 + 1]);
      acc[i * 8 + 2] = fmaf(av, wlo.z, acc[i * 8 + 2]);
      acc[i * 8 + 3] = fmaf(av, wlo.w, acc[i * 8 + 3]);
      acc[i * 8 + 4] = fmaf(av, whi.x, acc[i * 8 + 4]);
      acc[i * 8 + 5] = fmaf(av, whi.y, acc[i * 8 + 5]);
      acc[i * 8 + 6] = fmaf(av, whi.z, acc[i * 8 + 6]);
      acc[i * 8 + 7] = fmaf(av, whi.w, acc[i * 8 + 7]);
    }
  }
}

// GEMM: acc[8r x 8c] = A[16][4*NKQ] @ WT, W double-buffered (identical order to r8).
template <int NKQ>
__device__ __forceinline__ void gemm256(const float (*A)[256], const float* __restrict__ WT,
                                        float* acc, int gr8, int c0) {
  #pragma unroll
  for (int i = 0; i < 64; ++i) acc[i] = 0.f;
  float4 wA[8], wB[8];
  #pragma unroll
  for (int kk = 0; kk < 4; ++kk) {
    wA[kk * 2]     = *(const float4*)&WT[(size_t)kk * 256 + c0];
    wA[kk * 2 + 1] = *(const float4*)&WT[(size_t)kk * 256 + c0 + 4];
  }
  #pragma unroll 1
  for (int kq = 0; kq < NKQ; kq += 2) {
    #pragma unroll
    for (int kk = 0; kk < 4; ++kk) {
      wB[kk * 2]     = *(const float4*)&WT[(size_t)((kq + 1) * 4 + kk) * 256 + c0];
      wB[kk * 2 + 1] = *(const float4*)&WT[(size_t)((kq + 1) * 4 + kk) * 256 + c0 + 4];
    }
    quadf(A, kq, wA, acc, gr8);
    if (kq + 2 < NKQ) {
      #pragma unroll
      for (int kk = 0; kk < 4; ++kk) {
        wA[kk * 2]     = *(const float4*)&WT[(size_t)((kq + 2) * 4 + kk) * 256 + c0];
        wA[kk * 2 + 1] = *(const float4*)&WT[(size_t)((kq + 2) * 4 + kk) * 256 + c0 + 4];
      }
    }
    quadf(A, kq + 1, wB, acc, gr8);
  }
}

__device__ __forceinline__ void bias_relu(float* acc, const float* __restrict__ Bp, int c0) {
  float bv[8];
  *(float4*)&bv[0] = *(const float4*)&Bp[c0];
  *(float4*)&bv[4] = *(const float4*)&Bp[c0 + 4];
  #pragma unroll
  for (int rr = 0; rr < 8; ++rr)
    #pragma unroll
    for (int c = 0; c < 8; ++c)
      acc[rr * 8 + c] = fmaxf(acc[rr * 8 + c] + bv[c], 0.f);
}

// LayerNorm, centered two-pass (reference formula shape) — identical math to r8's ln64g;
// P36 = LDS scratch with row stride 36 (aliased into A rows 0..2).
__device__ __forceinline__ void ln64g(float* acc, float* P36,
                                      const float* __restrict__ gg,
                                      const float* __restrict__ bb,
                                      int l, int gr8, int c0) {
  const int ls = l & 31;
  float mu[8];
  // ---- pass 1: mean ----
  #pragma unroll
  for (int rr = 0; rr < 8; ++rr) {
    const float* a = &acc[rr * 8];
    P36[(gr8 + rr) * 36 + ls] =
        (((a[0] + a[1]) + (a[2] + a[3])) + ((a[4] + a[5]) + (a[6] + a[7])));
  }
  __syncthreads();
  if (l < 16) {
    float q[8];
    #pragma unroll
    for (int j = 0; j < 8; ++j) {
      const float4 u = *(const float4*)&P36[l * 36 + 4 * j];
      q[j] = (u.x + u.y) + (u.z + u.w);
    }
    const float s = ((q[0] + q[1]) + (q[2] + q[3])) + ((q[4] + q[5]) + (q[6] + q[7]));
    P36[l * 36 + 32] = s * (1.f / 256.f);
  }
  __syncthreads();
  #pragma unroll
  for (int rr = 0; rr < 8; ++rr) mu[rr] = P36[(gr8 + rr) * 36 + 32];   // broadcast
  __syncthreads();
  // ---- pass 2: centered variance ----
  #pragma unroll
  for (int rr = 0; rr < 8; ++rr) {
    const float* a = &acc[rr * 8];
    const float m = mu[rr];
    const float d0 = a[0] - m, d1 = a[1] - m, d2 = a[2] - m, d3 = a[3] - m;
    const float d4 = a[4] - m, d5 = a[5] - m, d6 = a[6] - m, d7 = a[7] - m;
    float s = d0 * d0;
    s = fmaf(d1, d1, s); s = fmaf(d2, d2, s); s = fmaf(d3, d3, s);
    s = fmaf(d4, d4, s); s = fmaf(d5, d5, s); s = fmaf(d6, d6, s); s = fmaf(d7, d7, s);
    P36[(gr8 + rr) * 36 + ls] = s;
  }
  __syncthreads();
  if (l < 16) {
    float q[8];
    #pragma unroll
    for (int j = 0; j < 8; ++j) {
      const float4 u = *(const float4*)&P36[l * 36 + 4 * j];
      q[j] = (u.x + u.y) + (u.z + u.w);
    }
    const float s2 = ((q[0] + q[1]) + (q[2] + q[3])) + ((q[4] + q[5]) + (q[6] + q[7]));
    P36[l * 36 + 32] = 1.f / sqrtf(s2 * (1.f / 256.f) + 1e-5f);
  }
  __syncthreads();
  // ---- normalize in registers: ((x-mu)*rs)*g + b ----
  float gv[8], bv[8];
  *(float4*)&gv[0] = *(const float4*)&gg[c0];
  *(float4*)&gv[4] = *(const float4*)&gg[c0 + 4];
  *(float4*)&bv[0] = *(const float4*)&bb[c0];
  *(float4*)&bv[4] = *(const float4*)&bb[c0 + 4];
  #pragma unroll
  for (int rr = 0; rr < 8; ++rr) {
    const float rs = P36[(gr8 + rr) * 36 + 32];
    const float m = mu[rr];
    #pragma unroll
    for (int c = 0; c < 8; ++c)
      acc[rr * 8 + c] = ((acc[rr * 8 + c] - m) * rs) * gv[c] + bv[c];
  }
}

__device__ __forceinline__ void storeA64g(float (*A)[256], const float* acc, int gr8, int c0) {
  #pragma unroll
  for (int rr = 0; rr < 8; ++rr) {
    *(float4*)&A[gr8 + rr][c0] =
        make_float4(acc[rr * 8], acc[rr * 8 + 1], acc[rr * 8 + 2], acc[rr * 8 + 3]);
    *(float4*)&A[gr8 + rr][c0 + 4] =
        make_float4(acc[rr * 8 + 4], acc[rr * 8 + 5], acc[rr * 8 + 6], acc[rr * 8 + 7]);
  }
}

// ==================== fused MLP kernel ====================
// blocks 0..31: decoder-table path (16 codebook rows each, 512 total)
// blocks 32..16415: encoder path (16 x-rows each)
__global__ __launch_bounds__(64, 2) void k_mlp(
    const float* __restrict__ x, const float* __restrict__ w0, const float* __restrict__ b0,
    const float* __restrict__ wt1, const float* __restrict__ wt2, const float* __restrict__ bh,
    const float* __restrict__ lng, const float* __restrict__ lnb,
    const float* __restrict__ wtout, const float* __restrict__ bout, float* __restrict__ z,
    const float* __restrict__ cb, const float* __restrict__ wt0d, const float* __restrict__ db0,
    const float* __restrict__ wtd1, const float* __restrict__ wtd2, const float* __restrict__ dbh,
    const float* __restrict__ dlng, const float* __restrict__ dlnb,
    const float* __restrict__ dwout, const float* __restrict__ dbout,
    float* __restrict__ table, float* __restrict__ ne) {
  __shared__ float A[16][256];
  float* Pa = &A[0][0];
  const int l = threadIdx.x;
  const int gr8 = (l >> 5) * 8;
  const int c0 = (l & 31) * 8;
  float acc[64];

  if (blockIdx.x >= 32) {
    // ================= encoder =================
    const size_t rbase = (size_t)(blockIdx.x - 32) * 16;
    { // layer 0: 3 -> 256, 8 rows x 8 cols per lane
      float wv[24], bv[8];
      #pragma unroll
      for (int i = 0; i < 6; ++i) *(float4*)&wv[i * 4] = *(const float4*)&w0[c0 * 3 + i * 4];
      *(float4*)&bv[0] = *(const float4*)&b0[c0];
      *(float4*)&bv[4] = *(const float4*)&b0[c0 + 4];
      #pragma unroll
      for (int rr = 0; rr < 8; ++rr) {
        const size_t r3 = (rbase + gr8 + rr) * 3;
        const float x0 = x[r3], x1 = x[r3 + 1], x2 = x[r3 + 2];
        #pragma unroll
        for (int c = 0; c < 8; ++c) {
          const float s = fmaf(wv[c * 3 + 2], x2, fmaf(wv[c * 3 + 1], x1, wv[c * 3] * x0));
          acc[rr * 8 + c] = fmaxf(s + bv[c], 0.f);
        }
      }
    }
    ln64g(acc, Pa, lng, lnb, l, gr8, c0);
    storeA64g(A, acc, gr8, c0);
    __syncthreads();

    gemm256<64>(A, wt1, acc, gr8, c0);
    bias_relu(acc, bh, c0);
    ln64g(acc, Pa, lng + 256, lnb + 256, l, gr8, c0);
    __syncthreads();
    storeA64g(A, acc, gr8, c0);
    __syncthreads();

    gemm256<64>(A, wt2, acc, gr8, c0);
    bias_relu(acc, bh + 256, c0);
    ln64g(acc, Pa, lng + 512, lnb + 512, l, gr8, c0);
    __syncthreads();
    storeA64g(A, acc, gr8, c0);
    __syncthreads();

    { // out layer 256 -> 64: 8 rows x 2 cols per lane
      const int c0o = (l & 31) * 2;
      float o[16];
      #pragma unroll
      for (int i = 0; i < 16; ++i) o[i] = 0.f;
      #pragma unroll 1
      for (int kq = 0; kq < 64; ++kq) {
        float4 a[8];
        #pragma unroll
        for (int i = 0; i < 8; ++i) a[i] = *(const float4*)&A[gr8 + i][kq * 4];
        #pragma unroll
        for (int kk = 0; kk < 4; ++kk) {
          const float2 wv = *(const float2*)&wtout[(size_t)(kq * 4 + kk) * 64 + c0o];
          #pragma unroll
          for (int i = 0; i < 8; ++i) {
            const float av = kk == 0 ? a[i].x : kk == 1 ? a[i].y : kk == 2 ? a[i].z : a[i].w;
            o[i * 2]     = fmaf(av, wv.x, o[i * 2]);
            o[i * 2 + 1] = fmaf(av, wv.y, o[i * 2 + 1]);
          }
        }
      }
      const float2 bb = *(const float2*)&bout[c0o];
      #pragma unroll
      for (int rr = 0; rr < 8; ++rr) {
        float2 st;
        st.x = o[rr * 2] + bb.x;
        st.y = o[rr * 2 + 1] + bb.y;
        *(float2*)&z[(rbase + gr8 + rr) * 64 + c0o] = st;
      }
    }
  } else {
    // ================= decoder table (dec(codebook)) =================
    const int cbase = blockIdx.x * 16;
    if (l < 16) { // ||e||^2, exact sequential chain (bit-identical to prior rounds)
      float s = 0.f;
      #pragma unroll 8
      for (int k = 0; k < 64; ++k) {
        const float v = cb[(size_t)(cbase + l) * 64 + k];
        s = fmaf(v, v, s);
      }
      ne[cbase + l] = s;
    }
    { // stage 16 codebook rows into A[r][0..63]
      const float4* cbf = (const float4*)(cb + (size_t)cbase * 64);
      const int r = l >> 2, q = l & 3;
      #pragma unroll
      for (int i = 0; i < 4; ++i)
        *(float4*)&A[r][q * 16 + i * 4] = cbf[r * 16 + q * 4 + i];
    }
    __syncthreads();

    gemm256<16>(A, wt0d, acc, gr8, c0);      // dec layer 0: 64 -> 256
    bias_relu(acc, db0, c0);
    ln64g(acc, Pa, dlng, dlnb, l, gr8, c0);
    __syncthreads();
    storeA64g(A, acc, gr8, c0);
    __syncthreads();

    gemm256<64>(A, wtd1, acc, gr8, c0);
    bias_relu(acc, dbh, c0);
    ln64g(acc, Pa, dlng + 256, dlnb + 256, l, gr8, c0);
    __syncthreads();
    storeA64g(A, acc, gr8, c0);
    __syncthreads();

    gemm256<64>(A, wtd2, acc, gr8, c0);
    bias_relu(acc, dbh + 256, c0);
    ln64g(acc, Pa, dlng + 512, dlnb + 512, l, gr8, c0);
    __syncthreads();
    storeA64g(A, acc, gr8, c0);
    __syncthreads();

    if (l < 16) { // final 256 -> 3, lane = row
      #pragma unroll
      for (int j = 0; j < 3; ++j) {
        float s = 0.f;
        #pragma unroll 4
        for (int kq = 0; kq < 64; ++kq) {
          const float4 w = *(const float4*)&dwout[j * 256 + kq * 4];
          const float4 a = *(const float4*)&A[l][kq * 4];
          s = fma4(w, a, s);
        }
        table[(cbase + l) * 3 + j] = s + dbout[j];
      }
    }
  }
}

// ---------------- weight transposes (enc + dec): WT[k][j] = W[j][k] ----------------
__global__ __launch_bounds__(256) void k_wt(
    const float* __restrict__ wh, const float* __restrict__ wout,
    const float* __restrict__ dwh, const float* __restrict__ dw0,
    float* __restrict__ wt1, float* __restrict__ wt2, float* __restrict__ wtout,
    float* __restrict__ wtd1, float* __restrict__ wtd2, float* __restrict__ wt0d) {
  const int b = blockIdx.x, t = threadIdx.x;
  if (b < 256) {
    wt1[b * 256 + t] = wh[t * 256 + b];
  } else if (b < 512) {
    const int k = b - 256;
    wt2[k * 256 + t] = wh[65536 + t * 256 + k];
  } else if (b < 576) {
    const int k = (b - 512) * 4 + (t >> 6);
    const int j = t & 63;
    wtout[k * 64 + j] = wout[j * 256 + k];
  } else if (b < 832) {
    const int k = b - 576;
    wtd1[k * 256 + t] = dwh[t * 256 + k];
  } else if (b < 1088) {
    const int k = b - 832;
    wtd2[k * 256 + t] = dwh[65536 + t * 256 + k];
  } else {
    const int k = b - 1088;               // 0..63
    wt0d[k * 256 + t] = dw0[t * 64 + k];
  }
}

// ---- VQ: z (in zq_io) -> argmin, quantized in-place, recon gather, partials ----
__global__ __launch_bounds__(256) void k_vq(
    float* __restrict__ zq_io, const float* __restrict__ cb,
    const float* __restrict__ ne, const float* __restrict__ table,
    const float* __restrict__ x, float* __restrict__ recon,
    float* __restrict__ psr, float* __restrict__ psv) {
  __shared__ float red[256];
  const int t = threadIdx.x;
  const int row = blockIdx.x * 256 + t;
  float4 zf[16];
  {
    const float4* zp = (const float4*)(zq_io + (size_t)row * 64);
    #pragma unroll
    for (int q = 0; q < 16; ++q) zf[q] = zp[q];
  }
  float nz = 0.f;
  #pragma unroll
  for (int q = 0; q < 16; ++q) {
    nz = fmaf(zf[q].x, zf[q].x, nz);
    nz = fmaf(zf[q].y, zf[q].y, nz);
    nz = fmaf(zf[q].z, zf[q].z, nz);
    nz = fmaf(zf[q].w, zf[q].w, nz);
  }
  float dmin = INFINITY; int imin = 0;
  const float4* cbv = (const float4*)cb;
  for (int c = 0; c < 512; ++c) {
    float da = 0.f, db = 0.f;
    #pragma unroll
    for (int q = 0; q < 16; q += 2) {
      const float4 ea = cbv[c * 16 + q];
      const float4 eb = cbv[c * 16 + q + 1];
      da = fmaf(ea.x, zf[q].x, da);
      da = fmaf(ea.y, zf[q].y, da);
      da = fmaf(ea.z, zf[q].z, da);
      da = fmaf(ea.w, zf[q].w, da);
      db = fmaf(eb.x, zf[q + 1].x, db);
      db = fmaf(eb.y, zf[q + 1].y, db);
      db = fmaf(eb.z, zf[q + 1].z, db);
      db = fmaf(eb.w, zf[q + 1].w, db);
    }
    const float dot = da + db;
    const float d = (nz + ne[c]) - 2.f * dot;
    if (d < dmin) { dmin = d; imin = c; }
  }
  float sv = 0.f;
  {
    const float4* eq = (const float4*)(cb + imin * 64);
    float4* qo = (float4*)(zq_io + (size_t)row * 64);
    #pragma unroll
    for (int q = 0; q < 16; ++q) {
      const float4 e = eq[q];
      const float4 zz = zf[q];
      const float ax = e.x - zz.x, ay = e.y - zz.y, az = e.z - zz.z, aw = e.w - zz.w;
      sv = fmaf(ax, ax, sv); sv = fmaf(ay, ay, sv);
      sv = fmaf(az, az, sv); sv = fmaf(aw, aw, sv);
      float4 st;
      st.x = zz.x + ax; st.y = zz.y + ay; st.z = zz.z + az; st.w = zz.w + aw;
      qo[q] = st;
    }
  }
  const float r0 = table[imin * 3], r1 = table[imin * 3 + 1], r2 = table[imin * 3 + 2];
  recon[row * 3] = r0; recon[row * 3 + 1] = r1; recon[row * 3 + 2] = r2;
  const float e0 = r0 - x[row * 3], e1 = r1 - x[row * 3 + 1], e2 = r2 - x[row * 3 + 2];
  const float sr = fmaf(e2, e2, fmaf(e1, e1, e0 * e0));
  red[t] = sr; __syncthreads();
  #pragma unroll
  for (int o = 128; o > 0; o >>= 1) { if (t < o) red[t] += red[t + o]; __syncthreads(); }
  if (t == 0) psr[blockIdx.x] = red[0];
  __syncthreads();
  red[t] = sv; __syncthreads();
  #pragma unroll
  for (int o = 128; o > 0; o >>= 1) { if (t < o) red[t] += red[t + o]; __syncthreads(); }
  if (t == 0) psv[blockIdx.x] = red[0];
}

// ---------------- final scalar loss ----------------
__global__ __launch_bounds__(256) void k_loss(
    const float* __restrict__ psr, const float* __restrict__ psv,
    float* __restrict__ out) {
  __shared__ float ra[256], rb[256];
  const int t = threadIdx.x;
  const float sr = ((psr[t] + psr[t + 256]) + psr[t + 512]) + psr[t + 768];
  const float sv = ((psv[t] + psv[t + 256]) + psv[t + 512]) + psv[t + 768];
  ra[t] = sr; rb[t] = sv;
  __syncthreads();
  #pragma unroll
  for (int o = 128; o > 0; o >>= 1) {
    if (t < o) { ra[t] += ra[t + o]; rb[t] += rb[t + o]; }
    __syncthreads();
  }
  if (t == 0) {
    const float mr = ra[0] / 786432.f;
    const float mv = rb[0] * (1.f / 16777216.f);
    const float vq = 0.25f * mv + mv;
    out[0] = mr + vq;
  }
}

extern "C" void kernel_launch(void* const* d_in, const int* in_sizes, int n_in,
                              void* d_out, int out_size, void* d_ws, size_t ws_size,
                              hipStream_t stream) {
  const float* x        = (const float*)d_in[0];
  const float* enc_w0   = (const float*)d_in[1];
  const float* enc_b0   = (const float*)d_in[2];
  const float* enc_wh   = (const float*)d_in[3];
  const float* enc_bh   = (const float*)d_in[4];
  const float* enc_lng  = (const float*)d_in[5];
  const float* enc_lnb  = (const float*)d_in[6];
  const float* enc_wout = (const float*)d_in[7];
  const float* enc_bout = (const float*)d_in[8];
  const float* cb       = (const float*)d_in[9];
  const float* dec_w0   = (const float*)d_in[10];
  const float* dec_b0   = (const float*)d_in[11];
  const float* dec_wh   = (const float*)d_in[12];
  const float* dec_bh   = (const float*)d_in[13];
  const float* dec_lng  = (const float*)d_in[14];
  const float* dec_lnb  = (const float*)d_in[15];
  const float* dec_wout = (const float*)d_in[16];
  const float* dec_bout = (const float*)d_in[17];

  float* out   = (float*)d_out;
  float* recon = out;                       // [N,3]
  float* qbuf  = out + 786432;              // [N,64]: z, then quantized in place
  float* lossp = out + 786432 + 16777216;   // scalar

  // Transposed weights live in the recon region (written before k_mlp reads them,
  // fully overwritten by k_vq afterwards -> deterministic across replays).
  float* wt1   = out;                       // 65536
  float* wt2   = out + 65536;               // 65536
  float* wtout = out + 131072;              // 16384
  float* wtd1  = out + 147456;              // 65536
  float* wtd2  = out + 212992;              // 65536
  float* wt0d  = out + 278528;              // 16384  (total 294912 < 786432)

  float* ws    = (float*)d_ws;
  float* ne    = ws;          // 512
  float* table = ws + 512;    // 512*3
  float* psr   = ws + 2048;   // 1024
  float* psv   = ws + 3072;   // 1024

  k_wt<<<1152, 256, 0, stream>>>(enc_wh, enc_wout, dec_wh, dec_w0,
                                 wt1, wt2, wtout, wtd1, wtd2, wt0d);
  k_mlp<<<16416, 64, 0, stream>>>(x, enc_w0, enc_b0, wt1, wt2, enc_bh,
                                  enc_lng, enc_lnb, wtout, enc_bout, qbuf,
                                  cb, wt0d, dec_b0, wtd1, wtd2, dec_bh,
                                  dec_lng, dec_lnb, dec_wout, dec_bout,
                                  table, ne);
  k_vq<<<1024, 256, 0, stream>>>(qbuf, cb, ne, table, x, recon, psr, psv);
  k_loss<<<1, 256, 0, stream>>>(psr, psv, lossp);
}